// Round 17
// baseline (624.923 us; speedup 1.0000x reference)
//
#include <hip/hip_runtime.h>
#include <hip/hip_bf16.h>
#include <math.h>

#define B_   32
#define S_   2048
#define H_   1024
#define K2H  2048           // 2H, GEMM K
#define M_TOT (B_*S_)       // 65536

typedef __attribute__((ext_vector_type(8))) short bf16x8;
typedef __attribute__((ext_vector_type(4))) float f32x4;

__device__ __forceinline__ short f2bf(float f) {
    union { float f; unsigned u; } c; c.f = f;
    unsigned u = c.u;
    unsigned r = u + 0x7FFFu + ((u >> 16) & 1u);
    return (short)(r >> 16);
}

__device__ __forceinline__ float ftanh(float x) {
    x = fminf(fmaxf(x, -15.f), 15.f);
    float e = __expf(2.f * x);
    return (e - 1.f) / (e + 1.f);
}

__device__ __forceinline__ void bar() {
    asm volatile("" ::: "memory");
    __builtin_amdgcn_s_barrier();
    asm volatile("" ::: "memory");
}

__device__ __forceinline__ void gload16(const short* g, short* l) {
    __builtin_amdgcn_global_load_lds(
        (const __attribute__((address_space(1))) void*)g,
        (__attribute__((address_space(3))) void*)l,
        16, 0, 0);
}

__device__ __forceinline__ void gload16f(const float* g, float* l) {
    __builtin_amdgcn_global_load_lds(
        (const __attribute__((address_space(1))) void*)g,
        (__attribute__((address_space(3))) void*)l,
        16, 0, 0);
}

// ==== small prep: W1->bf16 | dproj GEMV (enc conversion pass DELETED) ====
__global__ void prep_small(const float* __restrict__ Ww, short* __restrict__ w1,
                           const float* __restrict__ dec, const float* __restrict__ Wb,
                           float* __restrict__ dproj) {
    int bid = blockIdx.x;
    int t = threadIdx.x;
    if (bid < 2048) {
        int idx = bid * 256 + t;
        int e = idx * 4;
        int h = e >> 11;
        int k = e & 2047;
        float4 v = *reinterpret_cast<const float4*>(Ww + (size_t)h * 3072 + k);
        short4 o;
        o.x = f2bf(v.x); o.y = f2bf(v.y); o.z = f2bf(v.z); o.w = f2bf(v.w);
        *reinterpret_cast<short4*>(w1 + (size_t)h * 2048 + k) = o;
    } else {
        __shared__ float dl[1024];
        int db = bid - 2048;               // 0..511
        int b = db >> 4;
        int hc = db & 15;
        for (int i = t; i < 1024; i += 256) dl[i] = dec[b * 1024 + i];
        __syncthreads();
        int wv = t >> 6, lane = t & 63;
        for (int it = 0; it < 16; ++it) {
            int h = hc * 64 + wv * 16 + it;
            const float* wrow = Ww + (size_t)h * 3072 + 2048;
            float acc = 0.f;
            for (int j = lane; j < 1024; j += 64) acc += dl[j] * wrow[j];
            for (int m = 32; m >= 1; m >>= 1) acc += __shfl_xor(acc, m);
            if (lane == 0) dproj[b * 1024 + h] = acc + Wb[h];
        }
    }
}

// ==== 256x256xK GEMM: A staged fp32 via global_load_lds (cvt in-register),
//      B bf16; BK=32, ring-3, depth-2 prefetch, counted vmcnt(6/0),
//      1 barrier/K-tile, VMEM-in-MFMA SGB cadence ====
#define NT_ 64

// A: 32 KB/slot (256 rows x 32 f32). 4 units of 64 rows; thread -> row t>>3, chunk t&7.
#define STAGEA(dst, T) do { \
    _Pragma("unroll") \
    for (int u = 0; u < 4; ++u) { \
        int lr = u * 64 + sra; \
        int cs = (sca ^ (lr & 7)) * 4; \
        gload16f(abase + (size_t)lr * K2H + (T) * 32 + cs, (dst) + lr * 32 + sca * 4); \
    } } while (0)

// B: 16 KB/slot (256 rows x 32 bf16). 2 units of 128 rows; thread -> row t>>2, chunk t&3.
#define STAGEB(dst, T) do { \
    _Pragma("unroll") \
    for (int u = 0; u < 2; ++u) { \
        int lr = u * 128 + srb; \
        int cs = (scb ^ ((lr >> 1) & 3)) * 8; \
        gload16(bbase + (size_t)lr * K2H + (T) * 32 + cs, (dst) + lr * 32 + scb * 8); \
    } } while (0)

// read fp32 A fragment + convert to bf16x8 via v_cvt_pk_bf16_f32 (RNE)
#define RDAF(dstf, AS, roff) do { \
    _Pragma("unroll") \
    for (int ii = 0; ii < 4; ++ii) { \
        int R = wm * 128 + (roff) + ii * 16 + (lane & 15); \
        int rs_ = R & 7; \
        int kq_ = lane >> 4; \
        float4 lo_ = *reinterpret_cast<const float4*>(&(AS)[R * 32 + (((2*kq_)   ^ rs_) * 4)]); \
        float4 hi_ = *reinterpret_cast<const float4*>(&(AS)[R * 32 + (((2*kq_+1) ^ rs_) * 4)]); \
        union { unsigned u[4]; bf16x8 v8; } pk_; \
        asm("v_cvt_pk_bf16_f32 %0, %1, %2" : "=v"(pk_.u[0]) : "v"(lo_.x), "v"(lo_.y)); \
        asm("v_cvt_pk_bf16_f32 %0, %1, %2" : "=v"(pk_.u[1]) : "v"(lo_.z), "v"(lo_.w)); \
        asm("v_cvt_pk_bf16_f32 %0, %1, %2" : "=v"(pk_.u[2]) : "v"(hi_.x), "v"(hi_.y)); \
        asm("v_cvt_pk_bf16_f32 %0, %1, %2" : "=v"(pk_.u[3]) : "v"(hi_.z), "v"(hi_.w)); \
        dstf[ii] = pk_.v8; \
    } } while (0)

#define RDB(dstf, BS) do { \
    _Pragma("unroll") \
    for (int jj = 0; jj < 4; ++jj) { \
        int R = wn * 64 + jj * 16 + (lane & 15); \
        dstf[jj] = *reinterpret_cast<const bf16x8*>(&(BS)[R * 32 + (((lane >> 4) ^ ((R >> 1) & 3)) * 8)]); \
    } } while (0)

// one K-tile: frag reads+cvt; stage T+2 (slot last read at T-1, barrier-separated);
// 32 MFMA; SGB spreads the 6 DMAs ~1-per-5-MFMA; counted vmcnt; 1 barrier.
#define TILE(T, AS, BS, APF, BPF) do { \
    RDAF(aF, AS, 0); \
    RDB(bF, BS); \
    RDAF(aG, AS, 64); \
    if ((T) + 2 < NT_) { STAGEA(APF, (T) + 2); STAGEB(BPF, (T) + 2); } \
    __builtin_amdgcn_s_setprio(1); \
    _Pragma("unroll") for (int ii = 0; ii < 4; ++ii) \
      _Pragma("unroll") for (int jj = 0; jj < 4; ++jj) \
        acc[ii][jj] = __builtin_amdgcn_mfma_f32_16x16x32_bf16(aF[ii], bF[jj], acc[ii][jj], 0, 0, 0); \
    _Pragma("unroll") for (int ii = 0; ii < 4; ++ii) \
      _Pragma("unroll") for (int jj = 0; jj < 4; ++jj) \
        acc[4+ii][jj] = __builtin_amdgcn_mfma_f32_16x16x32_bf16(aG[ii], bF[jj], acc[4+ii][jj], 0, 0, 0); \
    __builtin_amdgcn_s_setprio(0); \
    __builtin_amdgcn_sched_group_barrier(0x008, 5, 0); \
    __builtin_amdgcn_sched_group_barrier(0x020, 1, 0); \
    __builtin_amdgcn_sched_group_barrier(0x008, 5, 0); \
    __builtin_amdgcn_sched_group_barrier(0x020, 1, 0); \
    __builtin_amdgcn_sched_group_barrier(0x008, 5, 0); \
    __builtin_amdgcn_sched_group_barrier(0x020, 1, 0); \
    __builtin_amdgcn_sched_group_barrier(0x008, 5, 0); \
    __builtin_amdgcn_sched_group_barrier(0x020, 1, 0); \
    __builtin_amdgcn_sched_group_barrier(0x008, 5, 0); \
    __builtin_amdgcn_sched_group_barrier(0x020, 1, 0); \
    __builtin_amdgcn_sched_group_barrier(0x008, 5, 0); \
    __builtin_amdgcn_sched_group_barrier(0x020, 1, 0); \
    __builtin_amdgcn_sched_group_barrier(0x008, 2, 0); \
    if ((T) <= NT_ - 3)      { asm volatile("s_waitcnt vmcnt(6)" ::: "memory"); } \
    else if ((T) == NT_ - 2) { asm volatile("s_waitcnt vmcnt(0)" ::: "memory"); } \
    bar(); \
} while (0)

__launch_bounds__(512, 1)
__global__ void fused_gemm8(const float* __restrict__ enc, const short* __restrict__ w1,
                            const float* __restrict__ dproj, const float* __restrict__ Vw,
                            float* __restrict__ scores_p) {
    __shared__ float A0[8192], A1[8192], A2[8192];   // 3 x 32 KB fp32
    __shared__ short B0[8192], B1[8192], B2[8192];   // 3 x 16 KB bf16
    int bid = blockIdx.x;
    int x = bid & 7, r = bid >> 3;
    int nt = r & 3;                    // 4 n-tiles (H/256)
    int mt = ((r >> 2) << 3) | x;      // 256 m-tiles, mt%8 == XCD
    int m0 = mt * 256, n0 = nt * 256;
    int t5 = threadIdx.x, lane = t5 & 63, wv = t5 >> 6;
    int wm = wv >> 2, wn = wv & 3;     // 2M x 4N waves; wave tile 128x64

    int sra = t5 >> 3, sca = t5 & 7;   // A staging map
    int srb = t5 >> 2, scb = t5 & 3;   // B staging map
    const float* abase = enc + (size_t)m0 * K2H;
    const short* bbase = w1 + (size_t)n0 * K2H;

    f32x4 acc[8][4] = {};
    bf16x8 aF[4], aG[4], bF[4];

    // prologue: stage tiles 0,1 (6 loads each); retire tile 0's 6
    STAGEA(A0, 0); STAGEB(B0, 0);
    STAGEA(A1, 1); STAGEB(B1, 1);
    asm volatile("s_waitcnt vmcnt(6)" ::: "memory");
    bar();

    for (int to = 0; to < 21; ++to) {
        int T = to * 3;
        TILE(T,     A0, B0, A2, B2);
        TILE(T + 1, A1, B1, A0, B0);
        TILE(T + 2, A2, B2, A1, B1);
    }
    TILE(63, A0, B0, A1, B1);   // tail: stage guards false

    // epilogue: part = Vw*ftanh(acc + dproj), reduce 64 n per wave, plain store
    int b = m0 >> 11;
    float dp[4], vvv[4];
#pragma unroll
    for (int j = 0; j < 4; ++j) {
        int hg = n0 + wn * 64 + j * 16 + (lane & 15);
        dp[j] = dproj[b * 1024 + hg];
        vvv[j] = Vw[hg];
    }
    float* sp = scores_p + (size_t)(nt * 4 + wn) * M_TOT;
#pragma unroll
    for (int i = 0; i < 8; ++i) {
#pragma unroll
        for (int q = 0; q < 4; ++q) {
            float part = 0.f;
#pragma unroll
            for (int j = 0; j < 4; ++j)
                part += vvv[j] * ftanh(acc[i][j][q] + dp[j]);
            part += __shfl_xor(part, 1);
            part += __shfl_xor(part, 2);
            part += __shfl_xor(part, 4);
            part += __shfl_xor(part, 8);
            if ((lane & 15) == 0) {
                int mg = m0 + wm * 128 + i * 16 + ((lane >> 4) << 2) + q;
                sp[mg] = part;
            }
        }
    }
}

// ---- coalesced 16-plane sum: scores[m] = sum_p scores_p[p][m] ----
__global__ void sumscores_kernel(const float* __restrict__ scores_p, float* __restrict__ scores) {
    int m = blockIdx.x * 256 + threadIdx.x;   // 256 blocks x 256 thr
    float s = 0.f;
#pragma unroll
    for (int p = 0; p < 16; ++p) s += scores_p[(size_t)p * M_TOT + m];
    scores[m] = s;
}

// ---- softmax over S per batch (on summed scores), mask-aware -> attn ----
__global__ void softmax_kernel(const float* __restrict__ scores, const float* __restrict__ mask,
                               float* __restrict__ attn) {
    int b = blockIdx.x;
    int t = threadIdx.x;
    __shared__ float red[8];
    __shared__ float red2[8];
    float v[8];
    float mx = -INFINITY;
#pragma unroll
    for (int k = 0; k < 8; ++k) {
        int s = t + k * 256;
        float xv = scores[b * 2048 + s];
        float mk = mask[b * 2048 + s];
        xv = (mk > 0.f) ? xv : -INFINITY;
        v[k] = xv;
        mx = fmaxf(mx, xv);
    }
    int lane = t & 63, wv = t >> 6;
    for (int m = 32; m >= 1; m >>= 1) mx = fmaxf(mx, __shfl_xor(mx, m));
    if (lane == 0) red[wv] = mx;
    __syncthreads();
    mx = fmaxf(fmaxf(red[0], red[1]), fmaxf(red[2], red[3]));
    float sum = 0.f;
#pragma unroll
    for (int k = 0; k < 8; ++k) { v[k] = __expf(v[k] - mx); sum += v[k]; }
    for (int m = 32; m >= 1; m >>= 1) sum += __shfl_xor(sum, m);
    if (lane == 0) red2[wv] = sum;
    __syncthreads();
    sum = red2[0] + red2[1] + red2[2] + red2[3];
    float inv = 1.f / sum;
#pragma unroll
    for (int k = 0; k < 8; ++k) attn[b * 2048 + t + k * 256] = v[k] * inv;
}

// ---- context[b,d] = sum_s attn[b,s] * enc[b,s,d] (fp32 enc) — atomic-free ----
// grid: 256 blocks = b(32) x dchunk(8 of 256 cols). Block owns out[b][dc*256..+256).
__global__ void context_kernel(const float* __restrict__ enc, const float* __restrict__ attn,
                               float* __restrict__ out) {
    __shared__ float aw[2048];        // full attn row (8 KB)
    __shared__ float red[8][256];     // cross-rowgroup reduce (8 KB)
    int bid = blockIdx.x;
    int b = bid >> 3;
    int dc = bid & 7;
    int t = threadIdx.x;
#pragma unroll
    for (int k = 0; k < 8; ++k) aw[t + k * 256] = attn[b * 2048 + t + k * 256];
    __syncthreads();
    int rgrp = t >> 5;                // 0..7: row-group (s = i*8 + rgrp)
    int cg = t & 31;                  // col-group: 8 cols at dc*256 + cg*8
    const float* base = enc + (size_t)b * S_ * K2H + dc * 256 + cg * 8;
    float acc[8] = {};
#pragma unroll 4
    for (int i = 0; i < 256; ++i) {
        int s = i * 8 + rgrp;
        float w = aw[s];
        float4 v0 = *reinterpret_cast<const float4*>(base + (size_t)s * K2H);
        float4 v1 = *reinterpret_cast<const float4*>(base + (size_t)s * K2H + 4);
        acc[0] += w * v0.x; acc[1] += w * v0.y; acc[2] += w * v0.z; acc[3] += w * v0.w;
        acc[4] += w * v1.x; acc[5] += w * v1.y; acc[6] += w * v1.z; acc[7] += w * v1.w;
    }
#pragma unroll
    for (int j = 0; j < 8; ++j) red[rgrp][cg * 8 + j] = acc[j];
    __syncthreads();
    float s = 0.f;
#pragma unroll
    for (int r2 = 0; r2 < 8; ++r2) s += red[r2][t];
    out[b * 2048 + dc * 256 + t] = s;
}

extern "C" void kernel_launch(void* const* d_in, const int* in_sizes, int n_in,
                              void* d_out, int out_size, void* d_ws, size_t ws_size,
                              hipStream_t stream) {
    const float* enc  = (const float*)d_in[0];   // (B,S,2H)
    const float* mask = (const float*)d_in[1];   // (B,S,1)
    const float* dec  = (const float*)d_in[2];   // (1,B,H)
    const float* Ww   = (const float*)d_in[3];   // (H,3H)
    const float* Wb   = (const float*)d_in[4];   // (H,)
    const float* Vw   = (const float*)d_in[5];   // (1,H)
    // V_b is softmax-invariant, skip.
    float* out = (float*)d_out;

    char* ws = (char*)d_ws;
    short* w1       = (short*)ws;                               // 4 MB bf16 W1
    float* scores_p = (float*)(ws + (4u << 20));                // 16 x 65536 fp32 = 4 MB
    float* dproj    = (float*)(ws + (8u << 20));                // 128 KB
    float* attn     = (float*)(ws + (8u << 20) + (128u << 10)); // 256 KB
    float* scores   = (float*)(ws + (8u << 20) + (384u << 10)); // 256 KB

    prep_small<<<2560, 256, 0, stream>>>(Ww, w1, dec, Wb, dproj);
    fused_gemm8<<<1024, 512, 0, stream>>>(enc, w1, dproj, Vw, scores_p);
    sumscores_kernel<<<256, 256, 0, stream>>>(scores_p, scores);
    softmax_kernel<<<32, 256, 0, stream>>>(scores, mask, attn);
    context_kernel<<<256, 256, 0, stream>>>(enc, attn, out);
}

// Round 18
// 576.976 us; speedup vs baseline: 1.0831x; 1.0831x over previous
//
#include <hip/hip_runtime.h>
#include <hip/hip_bf16.h>
#include <math.h>

#define B_   32
#define S_   2048
#define H_   1024
#define K2H  2048           // 2H, GEMM K
#define M_TOT (B_*S_)       // 65536

typedef __attribute__((ext_vector_type(8))) short bf16x8;
typedef __attribute__((ext_vector_type(4))) float f32x4;

__device__ __forceinline__ short f2bf(float f) {
    union { float f; unsigned u; } c; c.f = f;
    unsigned u = c.u;
    unsigned r = u + 0x7FFFu + ((u >> 16) & 1u);
    return (short)(r >> 16);
}

__device__ __forceinline__ float ftanh(float x) {
    x = fminf(fmaxf(x, -15.f), 15.f);
    float e = __expf(2.f * x);
    return (e - 1.f) / (e + 1.f);
}

__device__ __forceinline__ void bar() {
    asm volatile("" ::: "memory");
    __builtin_amdgcn_s_barrier();
    asm volatile("" ::: "memory");
}

__device__ __forceinline__ void gload16(const short* g, short* l) {
    __builtin_amdgcn_global_load_lds(
        (const __attribute__((address_space(1))) void*)g,
        (__attribute__((address_space(3))) void*)l,
        16, 0, 0);
}

// ==== merged prep: enc->bf16 | W1->bf16 | dproj GEMV, partitioned by blockIdx ====
__global__ void prep_kernel(const float* __restrict__ enc, short* __restrict__ encb,
                            const float* __restrict__ Ww, short* __restrict__ w1,
                            const float* __restrict__ dec, const float* __restrict__ Wb,
                            float* __restrict__ dproj) {
    int bid = blockIdx.x;
    int t = threadIdx.x;
    if (bid < 65536) {
        size_t e = ((size_t)bid * 256 + t) * 8;
        float4 v0 = *reinterpret_cast<const float4*>(enc + e);
        float4 v1 = *reinterpret_cast<const float4*>(enc + e + 4);
        short s[8];
        s[0]=f2bf(v0.x); s[1]=f2bf(v0.y); s[2]=f2bf(v0.z); s[3]=f2bf(v0.w);
        s[4]=f2bf(v1.x); s[5]=f2bf(v1.y); s[6]=f2bf(v1.z); s[7]=f2bf(v1.w);
        *reinterpret_cast<int4*>(encb + e) = *reinterpret_cast<const int4*>(s);
    } else if (bid < 65536 + 2048) {
        int idx = (bid - 65536) * 256 + t;
        int e = idx * 4;
        int h = e >> 11;
        int k = e & 2047;
        float4 v = *reinterpret_cast<const float4*>(Ww + (size_t)h * 3072 + k);
        short4 o;
        o.x = f2bf(v.x); o.y = f2bf(v.y); o.z = f2bf(v.z); o.w = f2bf(v.w);
        *reinterpret_cast<short4*>(w1 + (size_t)h * 2048 + k) = o;
    } else {
        __shared__ float dl[1024];
        int db = bid - 65536 - 2048;       // 0..511
        int b = db >> 4;
        int hc = db & 15;
        for (int i = t; i < 1024; i += 256) dl[i] = dec[b * 1024 + i];
        __syncthreads();
        int wv = t >> 6, lane = t & 63;
        for (int it = 0; it < 16; ++it) {
            int h = hc * 64 + wv * 16 + it;
            const float* wrow = Ww + (size_t)h * 3072 + 2048;
            float acc = 0.f;
            for (int j = lane; j < 1024; j += 64) acc += dl[j] * wrow[j];
            for (int m = 32; m >= 1; m >>= 1) acc += __shfl_xor(acc, m);
            if (lane == 0) dproj[b * 1024 + h] = acc + Wb[h];
        }
    }
}

// ==== 256x256xK GEMM (r12 config): BK=32, ring-4, depth-3 prefetch,
//      counted vmcnt(8/4/0), 1 barrier/K-tile, SGB cadence (1 VMEM / 8 MFMA) ====
#define NT_ 64

#define STAGE(dst, src, T) do { \
    _Pragma("unroll") \
    for (int u = 0; u < 2; ++u) { \
        int lr = u * 128 + sr; \
        int cs = (sc ^ ((lr >> 1) & 3)) * 8; \
        gload16((src) + (size_t)lr * K2H + (T) * 32 + cs, (dst) + lr * 32 + sc * 8); \
    } } while (0)

#define RDA(dstf, AS, roff) do { \
    _Pragma("unroll") \
    for (int ii = 0; ii < 4; ++ii) { \
        int R = wm * 128 + (roff) + ii * 16 + (lane & 15); \
        dstf[ii] = *reinterpret_cast<const bf16x8*>(&(AS)[R * 32 + (((lane >> 4) ^ ((R >> 1) & 3)) * 8)]); \
    } } while (0)

#define RDB(dstf, BS) do { \
    _Pragma("unroll") \
    for (int jj = 0; jj < 4; ++jj) { \
        int R = wn * 64 + jj * 16 + (lane & 15); \
        dstf[jj] = *reinterpret_cast<const bf16x8*>(&(BS)[R * 32 + (((lane >> 4) ^ ((R >> 1) & 3)) * 8)]); \
    } } while (0)

#define TILE(T, AS, BS, APF, BPF) do { \
    RDA(aF, AS, 0); \
    RDB(bF, BS); \
    RDA(aG, AS, 64); \
    if ((T) + 3 < NT_) { STAGE(APF, abase, (T) + 3); STAGE(BPF, bbase, (T) + 3); } \
    __builtin_amdgcn_s_setprio(1); \
    _Pragma("unroll") for (int ii = 0; ii < 4; ++ii) \
      _Pragma("unroll") for (int jj = 0; jj < 4; ++jj) \
        acc[ii][jj] = __builtin_amdgcn_mfma_f32_16x16x32_bf16(aF[ii], bF[jj], acc[ii][jj], 0, 0, 0); \
    _Pragma("unroll") for (int ii = 0; ii < 4; ++ii) \
      _Pragma("unroll") for (int jj = 0; jj < 4; ++jj) \
        acc[4+ii][jj] = __builtin_amdgcn_mfma_f32_16x16x32_bf16(aG[ii], bF[jj], acc[4+ii][jj], 0, 0, 0); \
    __builtin_amdgcn_s_setprio(0); \
    __builtin_amdgcn_sched_group_barrier(0x100, 12, 0); /* 12 ds_read first */ \
    __builtin_amdgcn_sched_group_barrier(0x008,  8, 0); \
    __builtin_amdgcn_sched_group_barrier(0x020,  1, 0); /* 1 global_load_lds */ \
    __builtin_amdgcn_sched_group_barrier(0x008,  8, 0); \
    __builtin_amdgcn_sched_group_barrier(0x020,  1, 0); \
    __builtin_amdgcn_sched_group_barrier(0x008,  8, 0); \
    __builtin_amdgcn_sched_group_barrier(0x020,  1, 0); \
    __builtin_amdgcn_sched_group_barrier(0x008,  8, 0); \
    __builtin_amdgcn_sched_group_barrier(0x020,  1, 0); \
    if ((T) <= NT_ - 4)      { asm volatile("s_waitcnt vmcnt(8)" ::: "memory"); } \
    else if ((T) == NT_ - 3) { asm volatile("s_waitcnt vmcnt(4)" ::: "memory"); } \
    else if ((T) == NT_ - 2) { asm volatile("s_waitcnt vmcnt(0)" ::: "memory"); } \
    bar(); \
} while (0)

__launch_bounds__(512, 1)
__global__ void fused_gemm8(const short* __restrict__ encb, const short* __restrict__ w1,
                            const float* __restrict__ dproj, const float* __restrict__ Vw,
                            float* __restrict__ scores_p) {
    __shared__ short A0[8192], A1[8192], A2[8192], A3[8192];   // 4 x 16 KB
    __shared__ short B0[8192], B1[8192], B2[8192], B3[8192];   // 4 x 16 KB
    int bid = blockIdx.x;
    int x = bid & 7, r = bid >> 3;
    int nt = r & 3;                    // 4 n-tiles (H/256)
    int mt = ((r >> 2) << 3) | x;      // 256 m-tiles, mt%8 == XCD
    int m0 = mt * 256, n0 = nt * 256;
    int t5 = threadIdx.x, lane = t5 & 63, wv = t5 >> 6;
    int wm = wv >> 2, wn = wv & 3;     // 2M x 4N waves; wave tile 128x64

    int sr = t5 >> 2;                  // staging row within 128-row unit
    int sc = t5 & 3;                   // staging 16B chunk
    const short* abase = encb + (size_t)m0 * K2H;
    const short* bbase = w1 + (size_t)n0 * K2H;

    f32x4 acc[8][4] = {};
    bf16x8 aF[4], aG[4], bF[4];

    // prologue: stage K-tiles 0..2, retire tile 0's 4
    STAGE(A0, abase, 0); STAGE(B0, bbase, 0);
    STAGE(A1, abase, 1); STAGE(B1, bbase, 1);
    STAGE(A2, abase, 2); STAGE(B2, bbase, 2);
    asm volatile("s_waitcnt vmcnt(8)" ::: "memory");
    bar();

    for (int to = 0; to < NT_ / 4; ++to) {
        int T = to * 4;
        TILE(T,     A0, B0, A3, B3);
        TILE(T + 1, A1, B1, A0, B0);
        TILE(T + 2, A2, B2, A1, B1);
        TILE(T + 3, A3, B3, A2, B2);
    }

    // epilogue: part = Vw*ftanh(acc + dproj), reduce 64 n per wave, plain store
    int b = m0 >> 11;
    float dp[4], vvv[4];
#pragma unroll
    for (int j = 0; j < 4; ++j) {
        int hg = n0 + wn * 64 + j * 16 + (lane & 15);
        dp[j] = dproj[b * 1024 + hg];
        vvv[j] = Vw[hg];
    }
    float* sp = scores_p + (size_t)(nt * 4 + wn) * M_TOT;
#pragma unroll
    for (int i = 0; i < 8; ++i) {
#pragma unroll
        for (int q = 0; q < 4; ++q) {
            float part = 0.f;
#pragma unroll
            for (int j = 0; j < 4; ++j)
                part += vvv[j] * ftanh(acc[i][j][q] + dp[j]);
            part += __shfl_xor(part, 1);
            part += __shfl_xor(part, 2);
            part += __shfl_xor(part, 4);
            part += __shfl_xor(part, 8);
            if ((lane & 15) == 0) {
                int mg = m0 + wm * 128 + i * 16 + ((lane >> 4) << 2) + q;
                sp[mg] = part;
            }
        }
    }
}

// ---- coalesced 16-plane sum: scores[m] = sum_p scores_p[p][m] ----
__global__ void sumscores_kernel(const float* __restrict__ scores_p, float* __restrict__ scores) {
    int m = blockIdx.x * 256 + threadIdx.x;   // 256 blocks x 256 thr
    float s = 0.f;
#pragma unroll
    for (int p = 0; p < 16; ++p) s += scores_p[(size_t)p * M_TOT + m];
    scores[m] = s;
}

// ---- softmax over S per batch (on summed scores), mask-aware -> attn ----
__global__ void softmax_kernel(const float* __restrict__ scores, const float* __restrict__ mask,
                               float* __restrict__ attn) {
    int b = blockIdx.x;
    int t = threadIdx.x;
    __shared__ float red[8];
    __shared__ float red2[8];
    float v[8];
    float mx = -INFINITY;
#pragma unroll
    for (int k = 0; k < 8; ++k) {
        int s = t + k * 256;
        float xv = scores[b * 2048 + s];
        float mk = mask[b * 2048 + s];
        xv = (mk > 0.f) ? xv : -INFINITY;
        v[k] = xv;
        mx = fmaxf(mx, xv);
    }
    int lane = t & 63, wv = t >> 6;
    for (int m = 32; m >= 1; m >>= 1) mx = fmaxf(mx, __shfl_xor(mx, m));
    if (lane == 0) red[wv] = mx;
    __syncthreads();
    mx = fmaxf(fmaxf(red[0], red[1]), fmaxf(red[2], red[3]));
    float sum = 0.f;
#pragma unroll
    for (int k = 0; k < 8; ++k) { v[k] = __expf(v[k] - mx); sum += v[k]; }
    for (int m = 32; m >= 1; m >>= 1) sum += __shfl_xor(sum, m);
    if (lane == 0) red2[wv] = sum;
    __syncthreads();
    sum = red2[0] + red2[1] + red2[2] + red2[3];
    float inv = 1.f / sum;
#pragma unroll
    for (int k = 0; k < 8; ++k) attn[b * 2048 + t + k * 256] = v[k] * inv;
}

// ---- context[b,d] = sum_s attn[b,s] * encb[b,s,d] — atomic-free, no memset ----
// grid: 256 blocks = b(32) x dchunk(8 of 256 cols). Block owns out[b][dc*256..+256).
__global__ void context_kernel(const short* __restrict__ encb, const float* __restrict__ attn,
                               float* __restrict__ out) {
    __shared__ float aw[2048];        // full attn row (8 KB)
    __shared__ float red[8][256];     // cross-rowgroup reduce (8 KB)
    int bid = blockIdx.x;
    int b = bid >> 3;
    int dc = bid & 7;
    int t = threadIdx.x;
#pragma unroll
    for (int k = 0; k < 8; ++k) aw[t + k * 256] = attn[b * 2048 + t + k * 256];
    __syncthreads();
    int rgrp = t >> 5;                // 0..7: row-group (s = i*8 + rgrp)
    int cg = t & 31;                  // col-group: 8 cols at dc*256 + cg*8
    const short* base = encb + (size_t)b * S_ * K2H + dc * 256 + cg * 8;
    float acc[8] = {};
#pragma unroll 4
    for (int i = 0; i < 256; ++i) {
        int s = i * 8 + rgrp;
        float w = aw[s];
        bf16x8 v = *reinterpret_cast<const bf16x8*>(base + (size_t)s * K2H);
#pragma unroll
        for (int j = 0; j < 8; ++j) {
            union { unsigned u; float f; } cv;
            cv.u = ((unsigned)(unsigned short)v[j]) << 16;
            acc[j] += w * cv.f;
        }
    }
#pragma unroll
    for (int j = 0; j < 8; ++j) red[rgrp][cg * 8 + j] = acc[j];
    __syncthreads();
    // thread t owns col t: sum the 8 row-group partials, plain store
    float s = 0.f;
#pragma unroll
    for (int r2 = 0; r2 < 8; ++r2) s += red[r2][t];
    out[b * 2048 + dc * 256 + t] = s;
}

extern "C" void kernel_launch(void* const* d_in, const int* in_sizes, int n_in,
                              void* d_out, int out_size, void* d_ws, size_t ws_size,
                              hipStream_t stream) {
    const float* enc  = (const float*)d_in[0];   // (B,S,2H)
    const float* mask = (const float*)d_in[1];   // (B,S,1)
    const float* dec  = (const float*)d_in[2];   // (1,B,H)
    const float* Ww   = (const float*)d_in[3];   // (H,3H)
    const float* Wb   = (const float*)d_in[4];   // (H,)
    const float* Vw   = (const float*)d_in[5];   // (1,H)
    // V_b is softmax-invariant, skip.
    float* out = (float*)d_out;

    char* ws = (char*)d_ws;
    const size_t ENC_B = (size_t)M_TOT * K2H * 2;            // 256 MB bf16 enc
    short* encb     = (short*)ws;
    short* w1       = (short*)(ws + ENC_B);                  // 4 MB
    float* scores_p = (float*)(ws + ENC_B + (4u << 20));     // 16 x 65536 fp32 = 4 MB
    float* dproj    = (float*)(ws + ENC_B + (8u << 20));     // 128 KB
    float* attn     = (float*)(ws + ENC_B + (8u << 20) + (128u << 10)); // 256 KB
    float* scores   = (float*)(ws + ENC_B + (8u << 20) + (384u << 10)); // 256 KB

    prep_kernel<<<68096, 256, 0, stream>>>(enc, encb, Ww, w1, dec, Wb, dproj);
    fused_gemm8<<<1024, 512, 0, stream>>>(encb, w1, dproj, Vw, scores_p);
    sumscores_kernel<<<256, 256, 0, stream>>>(scores_p, scores);
    softmax_kernel<<<32, 256, 0, stream>>>(scores, mask, attn);
    context_kernel<<<256, 256, 0, stream>>>(encb, attn, out);
}